// Round 13
// baseline (112.589 us; speedup 1.0000x reference)
//
#include <hip/hip_runtime.h>
#include <hip/hip_bf16.h>
#include <math.h>

typedef __bf16 bf16x8 __attribute__((ext_vector_type(8)));
typedef __bf16 bf16x4 __attribute__((ext_vector_type(4)));
typedef float  f32x4  __attribute__((ext_vector_type(4)));

#define NND 8192
#define DIM 64
#define PB  10368   // l2bf padded row stride (bf16): 20736 B = 81*256 B, channel-despread

__device__ __forceinline__ float wsum(float v) {
#pragma unroll
    for (int m = 1; m < 64; m <<= 1) v += __shfl_xor(v, m, 64);
    return v;
}

struct SC { float sh, ch; };
__device__ __forceinline__ SC sinhcosh(float c) {
    float e  = expf(c);
    float ei = 1.0f / e;
    SC r; r.sh = 0.5f * (e - ei); r.ch = 0.5f * (e + ei);
    return r;
}

__device__ __forceinline__ float arcosh_from_n2(float n2) {
    float t = fmaxf(n2, 2.0000001e-7f);
    return logf(sqrtf(1.0f + t) + sqrtf(t));
}

__device__ __forceinline__ float tangent_chain(float xv, int lane) {
    float y   = (lane == 0) ? 0.0f : xv;
    float yn2 = wsum(y * y);
    float yn  = fmaxf(sqrtf(fmaxf(yn2, 1e-30f)), 1e-15f);
    SC s1 = sinhcosh(fminf(yn, 15.0f));
    float r   = (lane == 0) ? 0.0f : s1.sh * y / yn;
    float rn2 = wsum(r * r);
    float ynb = fmaxf(sqrtf(fmaxf(rn2, 1e-30f)), 1e-15f);
    float ac  = arcosh_from_n2(rn2);
    return (lane == 0) ? 0.0f : ac * r / ynb;
}

__device__ __forceinline__ float second_chain(float m, float ubv, float theta_b, int lane) {
    float my  = (lane == 0) ? 0.0f : m;
    float mn2 = wsum(my * my);
    float mn  = fmaxf(sqrtf(fmaxf(mn2, 1e-30f)), 1e-15f);
    SC s2 = sinhcosh(fminf(mn, 15.0f));
    float rr   = (lane == 0) ? 0.0f : s2.sh * my / mn;
    float rrn2 = wsum(rr * rr);
    float res0 = sqrtf(fmaxf(1.0f + rrn2, 1e-7f));
    float yn3   = fmaxf(sqrtf(fmaxf(rrn2, 1e-30f)), 1e-15f);
    float yhat  = (lane == 0) ? 0.0f : rr / yn3;
    float alpha = wsum(yhat * ubv);
    float w_    = ubv - alpha * (1.0f - res0) * yhat;
    float ux    = wsum(rr * w_);
    float v0    = ux / fmaxf(res0, 1e-7f);
    float vv    = (lane == 0) ? v0 : w_;
    float resv  = (lane == 0) ? res0 : rr;
    float theta = theta_b;
    SC s3 = sinhcosh(fminf(theta, 15.0f));
    float pv  = s3.ch * resv + s3.sh * vv / theta;
    float pn2 = wsum((lane == 0) ? 0.0f : pv * pv);
    float yn4 = fmaxf(sqrtf(fmaxf(pn2, 1e-30f)), 1e-15f);
    float ac4 = arcosh_from_n2(pn2);
    return (lane == 0) ? 0.0f : ac4 * pv / yn4;
}

__device__ __forceinline__ float epilogue_chain(float hv, int lane) {
    float y   = (lane == 0) ? 0.0f : hv;
    float yn2 = wsum(y * y);
    float yn  = fmaxf(sqrtf(fmaxf(yn2, 1e-30f)), 1e-15f);
    SC s1 = sinhcosh(fminf(yn, 15.0f));
    float r   = (lane == 0) ? 0.0f : s1.sh * y / yn;
    float rn2 = wsum(r * r);
    float ynb = fmaxf(sqrtf(fmaxf(rn2, 1e-30f)), 1e-15f);
    float ac  = arcosh_from_n2(rn2);
    float lgv = (lane == 0) ? 0.0f : ac * r / ynb;
    float t   = (lgv > 0.0f) ? lgv : 0.01f * lgv;
    float tn2 = wsum(t * t);
    float tn  = fmaxf(sqrtf(fmaxf(tn2, 1e-30f)), 1e-15f);
    SC s3 = sinhcosh(fminf(tn, 15.0f));
    float ov  = (lane == 0) ? 0.0f : s3.sh * t / tn;
    float on2 = wsum(ov * ov);
    float o0  = sqrtf(fmaxf(1.0f + on2, 1e-7f));
    return (lane == 0) ? o0 : ov;
}

// Kernel 1: per-row chain + 64x64 matvec; 1 row per wave. (r12 verbatim, PB layout)
__global__ __launch_bounds__(256) void k_prep(
    const float* __restrict__ x, const float* __restrict__ weight,
    const float* __restrict__ bias, __bf16* __restrict__ l2bf)
{
    __shared__ float WL[64][65];
    const int tid  = threadIdx.x;
    const int lane = tid & 63;
    const int wave = tid >> 6;
#pragma unroll
    for (int i = 0; i < 16; ++i) {
        int idx = i * 256 + tid;
        WL[idx >> 6][idx & 63] = weight[idx];
    }
    __syncthreads();
    float ubv  = tangent_chain(bias[lane], lane);
    float nub2 = wsum(ubv * ubv);
    float thb  = fmaxf(fminf(sqrtf(fmaxf(nub2, 1e-7f)), 1e6f), 1e-15f);

    const int row = blockIdx.x * 4 + wave;
    float xv  = x[row * 64 + lane];
    float L1v = tangent_chain(xv, lane);
    float mj0 = 0.f, mj1 = 0.f, mj2 = 0.f, mj3 = 0.f;
#pragma unroll
    for (int d = 0; d < 64; d += 4) {
        mj0 = fmaf(__shfl(L1v, d,     64), WL[lane][d],     mj0);
        mj1 = fmaf(__shfl(L1v, d + 1, 64), WL[lane][d + 1], mj1);
        mj2 = fmaf(__shfl(L1v, d + 2, 64), WL[lane][d + 2], mj2);
        mj3 = fmaf(__shfl(L1v, d + 3, 64), WL[lane][d + 3], mj3);
    }
    float mj  = (mj0 + mj1) + (mj2 + mj3);
    float L2v = second_chain(mj, ubv, thb, lane);
    l2bf[(size_t)lane * PB + row] = (__bf16)L2v;
}

// Kernel 2: PROBE-SHAPED matmul. Block = 16 rows x 1024-k window.
// 4096 blocks = 512 row-sets (rows 512i+j, i=0..15) x 8 k-windows.
// Phase 1 = the measured-19.7TB/s probe verbatim: 16 independent back-to-back
// f32x4/lane loads, each wave-instr 4KB contiguous, stride 16MB.
// Phase 2: cvt->bf16, XOR-swizzled LDS write (issue-order consume).
// Phase 3 (after ONE barrier): waves own 16-dim d-blocks, 32 chained MFMAs,
// A via ds_read_b128 (pre-cvt'd), B from padded L2-hot l2bf. pws direct store.
__global__ __launch_bounds__(256, 2) void k_mm(
    const float* __restrict__ adj, const __bf16* __restrict__ l2bf,
    float* __restrict__ pws)
{
    __shared__ __bf16 AS[16 * 1024];        // 32 KB -> 2 blocks/CU
    const int tid  = threadIdx.x;
    const int lane = tid & 63;
    const int w    = tid >> 6;              // wave = d-block owner (dims 16w..16w+15)
    const int l15  = lane & 15;
    const int lg   = lane >> 4;
    const int j    = blockIdx.x >> 3;       // row offset 0..511
    const int kw8  = blockIdx.x & 7;        // k-window index
    const int kwin = kw8 * 1024;

    // ---- Phase 1: probe-shaped A stream (16 x 4KB contiguous stripes)
    f32x4 v[16];
#pragma unroll
    for (int i = 0; i < 16; ++i) {
        const float* gp = adj + (size_t)(512 * i + j) * NND + kwin + tid * 4;
        v[i] = *reinterpret_cast<const f32x4*>(gp);
    }

    // ---- Phase 2: cvt + swizzled LDS write (consume strictly in issue order)
    // row i holds 1024 bf16 = 128 x 16B chunks; chunk c swizzled by c ^ (i&7).
    const int c  = tid >> 1;                // chunk 0..127 (2 threads per chunk)
    const int h8 = (tid & 1) * 4;           // bf16 offset within chunk
#pragma unroll
    for (int i = 0; i < 16; ++i) {
        __bf16* dst = AS + i * 1024 + (c ^ (i & 7)) * 8 + h8;
        bf16x4 pv;
        pv[0] = (__bf16)v[i][0]; pv[1] = (__bf16)v[i][1];
        pv[2] = (__bf16)v[i][2]; pv[3] = (__bf16)v[i][3];
        *reinterpret_cast<bf16x4*>(dst) = pv;
    }
    __syncthreads();

    // ---- Phase 3: compute. Wave w -> output dims [16w, 16w+16), all 32 k-steps.
    const __bf16* bp = l2bf + (size_t)(16 * w + l15) * PB + kwin + 8 * lg;
    f32x4 acc = {0.f, 0.f, 0.f, 0.f};
#pragma unroll
    for (int ks = 0; ks < 32; ++ks) {
        const __bf16* ar = AS + l15 * 1024 + (((4 * ks + lg) ^ (l15 & 7)) * 8);
        bf16x8 a = *reinterpret_cast<const bf16x8*>(ar);
        bf16x8 b = *reinterpret_cast<const bf16x8*>(bp + 32 * ks);
        acc = __builtin_amdgcn_mfma_f32_16x16x32_bf16(a, b, acc, 0, 0, 0);
    }

    // ---- store partials: C/D col=l15 (dim), row=lg*4+i (LDS row ri -> global 512*ri+j)
    float* pp = pws + (size_t)kw8 * NND * DIM;
#pragma unroll
    for (int i = 0; i < 4; ++i) {
        const int ri = lg * 4 + i;
        pp[(size_t)(512 * ri + j) * DIM + 16 * w + l15] = acc[i];
    }
}

// Kernel 3: sum 8 k-window partials + fused epilogue. 1 row per wave.
__global__ __launch_bounds__(256) void k_fin(
    const float* __restrict__ pws, float* __restrict__ out)
{
    const int tid  = threadIdx.x;
    const int lane = tid & 63;
    const int wave = tid >> 6;
    const int row  = blockIdx.x * 4 + wave;
    const size_t base = (size_t)row * DIM + lane;
    const size_t S = (size_t)NND * DIM;
    float hv = (((pws[base] + pws[S + base]) + (pws[2*S + base] + pws[3*S + base]))
             +  ((pws[4*S + base] + pws[5*S + base]) + (pws[6*S + base] + pws[7*S + base])));
    out[base] = epilogue_chain(hv, lane);
}

extern "C" void kernel_launch(void* const* d_in, const int* in_sizes, int n_in,
                              void* d_out, int out_size, void* d_ws, size_t ws_size,
                              hipStream_t stream)
{
    const float* x      = (const float*)d_in[0];
    const float* adj    = (const float*)d_in[1];
    const float* weight = (const float*)d_in[2];
    const float* bias   = (const float*)d_in[3];
    float* out = (float*)d_out;
    __bf16* l2bf = (__bf16*)d_ws;                          // 64 x PB bf16 = 1.33 MB
    float*  pws  = (float*)((char*)d_ws + 0x180000);       // 8 x 2 MB partials

    k_prep<<<2048, 256, 0, stream>>>(x, weight, bias, l2bf);
    k_mm<<<4096, 256, 0, stream>>>(adj, l2bf, pws);
    k_fin<<<2048, 256, 0, stream>>>(pws, out);
}

// Round 14
// 97.260 us; speedup vs baseline: 1.1576x; 1.1576x over previous
//
#include <hip/hip_runtime.h>
#include <hip/hip_bf16.h>
#include <math.h>

typedef __bf16 bf16x8 __attribute__((ext_vector_type(8)));
typedef __bf16 bf16x4 __attribute__((ext_vector_type(4)));
typedef float  f32x4  __attribute__((ext_vector_type(4)));

#define NND 8192
#define DIM 64
#define PB  10368   // l2bf padded row stride (bf16): 20736 B = 81*256 B
#define KW  512     // k-window per block
#define NKW 16      // number of k-windows

__device__ __forceinline__ float wsum(float v) {
#pragma unroll
    for (int m = 1; m < 64; m <<= 1) v += __shfl_xor(v, m, 64);
    return v;
}

struct SC { float sh, ch; };
__device__ __forceinline__ SC sinhcosh(float c) {
    float e  = expf(c);
    float ei = 1.0f / e;
    SC r; r.sh = 0.5f * (e - ei); r.ch = 0.5f * (e + ei);
    return r;
}

__device__ __forceinline__ float arcosh_from_n2(float n2) {
    float t = fmaxf(n2, 2.0000001e-7f);
    return logf(sqrtf(1.0f + t) + sqrtf(t));
}

__device__ __forceinline__ float tangent_chain(float xv, int lane) {
    float y   = (lane == 0) ? 0.0f : xv;
    float yn2 = wsum(y * y);
    float yn  = fmaxf(sqrtf(fmaxf(yn2, 1e-30f)), 1e-15f);
    SC s1 = sinhcosh(fminf(yn, 15.0f));
    float r   = (lane == 0) ? 0.0f : s1.sh * y / yn;
    float rn2 = wsum(r * r);
    float ynb = fmaxf(sqrtf(fmaxf(rn2, 1e-30f)), 1e-15f);
    float ac  = arcosh_from_n2(rn2);
    return (lane == 0) ? 0.0f : ac * r / ynb;
}

__device__ __forceinline__ float second_chain(float m, float ubv, float theta_b, int lane) {
    float my  = (lane == 0) ? 0.0f : m;
    float mn2 = wsum(my * my);
    float mn  = fmaxf(sqrtf(fmaxf(mn2, 1e-30f)), 1e-15f);
    SC s2 = sinhcosh(fminf(mn, 15.0f));
    float rr   = (lane == 0) ? 0.0f : s2.sh * my / mn;
    float rrn2 = wsum(rr * rr);
    float res0 = sqrtf(fmaxf(1.0f + rrn2, 1e-7f));
    float yn3   = fmaxf(sqrtf(fmaxf(rrn2, 1e-30f)), 1e-15f);
    float yhat  = (lane == 0) ? 0.0f : rr / yn3;
    float alpha = wsum(yhat * ubv);
    float w_    = ubv - alpha * (1.0f - res0) * yhat;
    float ux    = wsum(rr * w_);
    float v0    = ux / fmaxf(res0, 1e-7f);
    float vv    = (lane == 0) ? v0 : w_;
    float resv  = (lane == 0) ? res0 : rr;
    float theta = theta_b;
    SC s3 = sinhcosh(fminf(theta, 15.0f));
    float pv  = s3.ch * resv + s3.sh * vv / theta;
    float pn2 = wsum((lane == 0) ? 0.0f : pv * pv);
    float yn4 = fmaxf(sqrtf(fmaxf(pn2, 1e-30f)), 1e-15f);
    float ac4 = arcosh_from_n2(pn2);
    return (lane == 0) ? 0.0f : ac4 * pv / yn4;
}

__device__ __forceinline__ float epilogue_chain(float hv, int lane) {
    float y   = (lane == 0) ? 0.0f : hv;
    float yn2 = wsum(y * y);
    float yn  = fmaxf(sqrtf(fmaxf(yn2, 1e-30f)), 1e-15f);
    SC s1 = sinhcosh(fminf(yn, 15.0f));
    float r   = (lane == 0) ? 0.0f : s1.sh * y / yn;
    float rn2 = wsum(r * r);
    float ynb = fmaxf(sqrtf(fmaxf(rn2, 1e-30f)), 1e-15f);
    float ac  = arcosh_from_n2(rn2);
    float lgv = (lane == 0) ? 0.0f : ac * r / ynb;
    float t   = (lgv > 0.0f) ? lgv : 0.01f * lgv;
    float tn2 = wsum(t * t);
    float tn  = fmaxf(sqrtf(fmaxf(tn2, 1e-30f)), 1e-15f);
    SC s3 = sinhcosh(fminf(tn, 15.0f));
    float ov  = (lane == 0) ? 0.0f : s3.sh * t / tn;
    float on2 = wsum(ov * ov);
    float o0  = sqrtf(fmaxf(1.0f + on2, 1e-7f));
    return (lane == 0) ? o0 : ov;
}

// Kernel 1: per-row chain + 64x64 matvec; 1 row per wave. (PB layout)
__global__ __launch_bounds__(256) void k_prep(
    const float* __restrict__ x, const float* __restrict__ weight,
    const float* __restrict__ bias, __bf16* __restrict__ l2bf)
{
    __shared__ float WL[64][65];
    const int tid  = threadIdx.x;
    const int lane = tid & 63;
    const int wave = tid >> 6;
#pragma unroll
    for (int i = 0; i < 16; ++i) {
        int idx = i * 256 + tid;
        WL[idx >> 6][idx & 63] = weight[idx];
    }
    __syncthreads();
    float ubv  = tangent_chain(bias[lane], lane);
    float nub2 = wsum(ubv * ubv);
    float thb  = fmaxf(fminf(sqrtf(fmaxf(nub2, 1e-7f)), 1e6f), 1e-15f);

    const int row = blockIdx.x * 4 + wave;
    float xv  = x[row * 64 + lane];
    float L1v = tangent_chain(xv, lane);
    float mj0 = 0.f, mj1 = 0.f, mj2 = 0.f, mj3 = 0.f;
#pragma unroll
    for (int d = 0; d < 64; d += 4) {
        mj0 = fmaf(__shfl(L1v, d,     64), WL[lane][d],     mj0);
        mj1 = fmaf(__shfl(L1v, d + 1, 64), WL[lane][d + 1], mj1);
        mj2 = fmaf(__shfl(L1v, d + 2, 64), WL[lane][d + 2], mj2);
        mj3 = fmaf(__shfl(L1v, d + 3, 64), WL[lane][d + 3], mj3);
    }
    float mj  = (mj0 + mj1) + (mj2 + mj3);
    float L2v = second_chain(mj, ubv, thb, lane);
    l2bf[(size_t)lane * PB + row] = (__bf16)L2v;
}

// Kernel 2: h_tan partials. Block = 256 rows x 512-k window; 512 blocks =
// 32 rowgroups x 16 kwin. B window staged ONCE in LDS (64KB, swizzled);
// A reg-prefetched probe-style into double-buffered LDS (2x32KB). The MFMA
// loop touches ONLY LDS — zero in-loop global reads. Waves = rowhalf x
// dimquarter -> acc is final per window, stored directly (no cross-wave reduce).
__global__ __launch_bounds__(512, 2) void k_mm(
    const float* __restrict__ adj, const __bf16* __restrict__ l2bf,
    float* __restrict__ pws)
{
    __shared__ __bf16 Bs[64 * KW];          // 64 KB
    __shared__ __bf16 As[2][32 * KW];       // 2 x 32 KB
    const int tid  = threadIdx.x;
    const int lane = tid & 63;
    const int w    = tid >> 6;              // wave 0..7
    const int l15  = lane & 15;
    const int lg   = lane >> 4;
    const int rh   = w >> 2;                // row-half (0..1)
    const int dq   = w & 3;                 // dim-quarter (0..3)
    const int kw   = blockIdx.x & 15;       // k-window; same-kw blocks -> same XCD
    const int rg   = blockIdx.x >> 4;       // row-group 0..31
    const int R0   = rg * 256;
    const int kwin = kw * KW;

    // ---- prologue: issue B-window loads + A(group 0) loads back-to-back
    bf16x8 bv[8];
#pragma unroll
    for (int i = 0; i < 8; ++i) {           // 64x512 bf16: 1KB contiguous per instr
        const int f = i * 512 + tid;
        const int row = f >> 6, c = f & 63;
        bv[i] = *reinterpret_cast<const bf16x8*>(l2bf + (size_t)row * PB + kwin + c * 8);
    }
    f32x4 v[8];
#pragma unroll
    for (int i = 0; i < 8; ++i) {           // 32x512 f32: 1KB contiguous per instr
        const int f = i * 512 + tid;
        const int row = f >> 7, q = f & 127;
        v[i] = *reinterpret_cast<const f32x4*>(adj + (size_t)(R0 + row) * NND + kwin + q * 4);
    }
#pragma unroll
    for (int i = 0; i < 8; ++i) {           // B -> LDS, chunk XOR swizzle
        const int f = i * 512 + tid;
        const int row = f >> 6, c = f & 63;
        *reinterpret_cast<bf16x8*>(Bs + row * KW + ((c ^ (row & 7)) * 8)) = bv[i];
    }
#pragma unroll
    for (int i = 0; i < 8; ++i) {           // A(0) cvt -> LDS buf0
        const int f = i * 512 + tid;
        const int row = f >> 7, q = f & 127;
        bf16x4 pv;
        pv[0] = (__bf16)v[i][0]; pv[1] = (__bf16)v[i][1];
        pv[2] = (__bf16)v[i][2]; pv[3] = (__bf16)v[i][3];
        *reinterpret_cast<bf16x4*>(As[0] + row * KW + (((q >> 1) ^ (row & 7)) * 8) + (q & 1) * 4) = pv;
    }
    __syncthreads();

    float* pp = pws + (size_t)kw * NND * DIM;

    for (int g = 0; g < 8; ++g) {
        const __bf16* Ab = As[g & 1];
        f32x4 nv[8];
        if (g < 7) {                        // issue A(g+1) EARLY (oldest in FIFO)
#pragma unroll
            for (int i = 0; i < 8; ++i) {
                const int f = i * 512 + tid;
                const int row = f >> 7, q = f & 127;
                nv[i] = *reinterpret_cast<const f32x4*>(
                    adj + (size_t)(R0 + (g + 1) * 32 + row) * NND + kwin + q * 4);
            }
        }
        // compute group g: 16 chained MFMAs, all operands from LDS
        f32x4 acc = {0.f, 0.f, 0.f, 0.f};
#pragma unroll
        for (int ks = 0; ks < 16; ++ks) {
            const int c = ks * 4 + lg;
            bf16x8 a = *reinterpret_cast<const bf16x8*>(
                Ab + (rh * 16 + l15) * KW + ((c ^ (l15 & 7)) * 8));
            bf16x8 b = *reinterpret_cast<const bf16x8*>(
                Bs + (dq * 16 + l15) * KW + ((c ^ (l15 & 7)) * 8));
            acc = __builtin_amdgcn_mfma_f32_16x16x32_bf16(a, b, acc, 0, 0, 0);
        }
        // store: C/D col=l15 (dim within quarter), row=lg*4+i
#pragma unroll
        for (int i = 0; i < 4; ++i) {
            const int grow = R0 + g * 32 + rh * 16 + lg * 4 + i;
            pp[(size_t)grow * DIM + dq * 16 + l15] = acc[i];
        }
        if (g < 7) {                        // cvt + write A(g+1) into other buffer
            __bf16* An = As[(g + 1) & 1];
#pragma unroll
            for (int i = 0; i < 8; ++i) {
                const int f = i * 512 + tid;
                const int row = f >> 7, q = f & 127;
                bf16x4 pv;
                pv[0] = (__bf16)nv[i][0]; pv[1] = (__bf16)nv[i][1];
                pv[2] = (__bf16)nv[i][2]; pv[3] = (__bf16)nv[i][3];
                *reinterpret_cast<bf16x4*>(An + row * KW + (((q >> 1) ^ (row & 7)) * 8) + (q & 1) * 4) = pv;
            }
        }
        __syncthreads();
    }
}

// Kernel 3: sum 16 k-window partials + fused epilogue. 1 row per wave.
__global__ __launch_bounds__(256) void k_fin(
    const float* __restrict__ pws, float* __restrict__ out)
{
    const int tid  = threadIdx.x;
    const int lane = tid & 63;
    const int wave = tid >> 6;
    const int row  = blockIdx.x * 4 + wave;
    const size_t base = (size_t)row * DIM + lane;
    const size_t S = (size_t)NND * DIM;
    float hv = 0.0f;
#pragma unroll
    for (int s = 0; s < NKW; ++s) hv += pws[s * S + base];
    out[base] = epilogue_chain(hv, lane);
}

extern "C" void kernel_launch(void* const* d_in, const int* in_sizes, int n_in,
                              void* d_out, int out_size, void* d_ws, size_t ws_size,
                              hipStream_t stream)
{
    const float* x      = (const float*)d_in[0];
    const float* adj    = (const float*)d_in[1];
    const float* weight = (const float*)d_in[2];
    const float* bias   = (const float*)d_in[3];
    float* out = (float*)d_out;
    __bf16* l2bf = (__bf16*)d_ws;                          // 64 x PB bf16 = 1.33 MB
    float*  pws  = (float*)((char*)d_ws + 0x180000);       // 16 x 2 MB partials

    k_prep<<<2048, 256, 0, stream>>>(x, weight, bias, l2bf);
    k_mm<<<512, 512, 0, stream>>>(adj, l2bf, pws);
    k_fin<<<2048, 256, 0, stream>>>(pws, out);
}

// Round 15
// 96.312 us; speedup vs baseline: 1.1690x; 1.0098x over previous
//
#include <hip/hip_runtime.h>
#include <hip/hip_bf16.h>
#include <math.h>

typedef __bf16 bf16x8 __attribute__((ext_vector_type(8)));
typedef __bf16 bf16x4 __attribute__((ext_vector_type(4)));
typedef float  f32x4  __attribute__((ext_vector_type(4)));

#define NND 8192
#define DIM 64
#define PB  10368   // l2bf padded row stride (bf16): 20736 B = 81*256 B

__device__ __forceinline__ float wsum(float v) {
#pragma unroll
    for (int m = 1; m < 64; m <<= 1) v += __shfl_xor(v, m, 64);
    return v;
}

struct SC { float sh, ch; };
__device__ __forceinline__ SC sinhcosh(float c) {
    float e  = expf(c);
    float ei = 1.0f / e;
    SC r; r.sh = 0.5f * (e - ei); r.ch = 0.5f * (e + ei);
    return r;
}

__device__ __forceinline__ float arcosh_from_n2(float n2) {
    float t = fmaxf(n2, 2.0000001e-7f);
    return logf(sqrtf(1.0f + t) + sqrtf(t));
}

__device__ __forceinline__ float tangent_chain(float xv, int lane) {
    float y   = (lane == 0) ? 0.0f : xv;
    float yn2 = wsum(y * y);
    float yn  = fmaxf(sqrtf(fmaxf(yn2, 1e-30f)), 1e-15f);
    SC s1 = sinhcosh(fminf(yn, 15.0f));
    float r   = (lane == 0) ? 0.0f : s1.sh * y / yn;
    float rn2 = wsum(r * r);
    float ynb = fmaxf(sqrtf(fmaxf(rn2, 1e-30f)), 1e-15f);
    float ac  = arcosh_from_n2(rn2);
    return (lane == 0) ? 0.0f : ac * r / ynb;
}

__device__ __forceinline__ float second_chain(float m, float ubv, float theta_b, int lane) {
    float my  = (lane == 0) ? 0.0f : m;
    float mn2 = wsum(my * my);
    float mn  = fmaxf(sqrtf(fmaxf(mn2, 1e-30f)), 1e-15f);
    SC s2 = sinhcosh(fminf(mn, 15.0f));
    float rr   = (lane == 0) ? 0.0f : s2.sh * my / mn;
    float rrn2 = wsum(rr * rr);
    float res0 = sqrtf(fmaxf(1.0f + rrn2, 1e-7f));
    float yn3   = fmaxf(sqrtf(fmaxf(rrn2, 1e-30f)), 1e-15f);
    float yhat  = (lane == 0) ? 0.0f : rr / yn3;
    float alpha = wsum(yhat * ubv);
    float w_    = ubv - alpha * (1.0f - res0) * yhat;
    float ux    = wsum(rr * w_);
    float v0    = ux / fmaxf(res0, 1e-7f);
    float vv    = (lane == 0) ? v0 : w_;
    float resv  = (lane == 0) ? res0 : rr;
    float theta = theta_b;
    SC s3 = sinhcosh(fminf(theta, 15.0f));
    float pv  = s3.ch * resv + s3.sh * vv / theta;
    float pn2 = wsum((lane == 0) ? 0.0f : pv * pv);
    float yn4 = fmaxf(sqrtf(fmaxf(pn2, 1e-30f)), 1e-15f);
    float ac4 = arcosh_from_n2(pn2);
    return (lane == 0) ? 0.0f : ac4 * pv / yn4;
}

__device__ __forceinline__ float epilogue_chain(float hv, int lane) {
    float y   = (lane == 0) ? 0.0f : hv;
    float yn2 = wsum(y * y);
    float yn  = fmaxf(sqrtf(fmaxf(yn2, 1e-30f)), 1e-15f);
    SC s1 = sinhcosh(fminf(yn, 15.0f));
    float r   = (lane == 0) ? 0.0f : s1.sh * y / yn;
    float rn2 = wsum(r * r);
    float ynb = fmaxf(sqrtf(fmaxf(rn2, 1e-30f)), 1e-15f);
    float ac  = arcosh_from_n2(rn2);
    float lgv = (lane == 0) ? 0.0f : ac * r / ynb;
    float t   = (lgv > 0.0f) ? lgv : 0.01f * lgv;
    float tn2 = wsum(t * t);
    float tn  = fmaxf(sqrtf(fmaxf(tn2, 1e-30f)), 1e-15f);
    SC s3 = sinhcosh(fminf(tn, 15.0f));
    float ov  = (lane == 0) ? 0.0f : s3.sh * t / tn;
    float on2 = wsum(ov * ov);
    float o0  = sqrtf(fmaxf(1.0f + on2, 1e-7f));
    return (lane == 0) ? o0 : ov;
}

// Kernel 1: per-row chain + 64x64 matvec; 1 row per wave. (PB layout, unchanged)
__global__ __launch_bounds__(256) void k_prep(
    const float* __restrict__ x, const float* __restrict__ weight,
    const float* __restrict__ bias, __bf16* __restrict__ l2bf)
{
    __shared__ float WL[64][65];
    const int tid  = threadIdx.x;
    const int lane = tid & 63;
    const int wave = tid >> 6;
#pragma unroll
    for (int i = 0; i < 16; ++i) {
        int idx = i * 256 + tid;
        WL[idx >> 6][idx & 63] = weight[idx];
    }
    __syncthreads();
    float ubv  = tangent_chain(bias[lane], lane);
    float nub2 = wsum(ubv * ubv);
    float thb  = fmaxf(fminf(sqrtf(fmaxf(nub2, 1e-7f)), 1e6f), 1e-15f);

    const int row = blockIdx.x * 4 + wave;
    float xv  = x[row * 64 + lane];
    float L1v = tangent_chain(xv, lane);
    float mj0 = 0.f, mj1 = 0.f, mj2 = 0.f, mj3 = 0.f;
#pragma unroll
    for (int d = 0; d < 64; d += 4) {
        mj0 = fmaf(__shfl(L1v, d,     64), WL[lane][d],     mj0);
        mj1 = fmaf(__shfl(L1v, d + 1, 64), WL[lane][d + 1], mj1);
        mj2 = fmaf(__shfl(L1v, d + 2, 64), WL[lane][d + 2], mj2);
        mj3 = fmaf(__shfl(L1v, d + 3, 64), WL[lane][d + 3], mj3);
    }
    float mj  = (mj0 + mj1) + (mj2 + mj3);
    float L2v = second_chain(mj, ubv, thb, lane);
    l2bf[(size_t)lane * PB + row] = (__bf16)L2v;
}

// Kernel 2: OCCUPANCY build — 32 waves/CU (8 blocks x 4 waves per CU).
// Grid 2048 = 256 rowgroups (32 rows) x 8 k-windows (1024 k). Waves own
// 16-dim quarters; bf16 A-tiles in 17KB LDS (no inner-loop cvt); VGPR<=64 via
// launch_bounds(256,8); ONE barrier per tile. Per-CU BW = waves x ~1 B/cy.
__global__ __launch_bounds__(256, 8) void k_mm(
    const float* __restrict__ adj, const __bf16* __restrict__ l2bf,
    float* __restrict__ pws)
{
    __shared__ __bf16 As[2][32][136];    // 17408 B -> 8 blocks/CU
    const int tid  = threadIdx.x;
    const int lane = tid & 63;
    const int w    = tid >> 6;           // dim-quarter owner (dims 16w..16w+15)
    const int l15  = lane & 15;
    const int lg   = lane >> 4;
    const int kw   = blockIdx.x & 7;     // k-window (fast -> XCD spread)
    const int rg   = blockIdx.x >> 3;    // row-group 0..255
    const int R0   = rg * 32;
    const int kbase = kw * 1024;

    const int srow = tid >> 5;           // staging: rows srow, +8, +16, +24
    const int scol = (tid & 31) * 4;     // cols scol..scol+3 (floats)

    const __bf16* bp = l2bf + (size_t)(16 * w + l15) * PB + kbase + 8 * lg;
    const float*  gA = adj + (size_t)(R0 + srow) * NND + kbase + scol;

    f32x4 accL = {0.f, 0.f, 0.f, 0.f};
    f32x4 accH = accL;

    // ---- prologue: stage tile 0 (32 rows x 128 k) as bf16
    {
        f32x4 s0 = *reinterpret_cast<const f32x4*>(gA);
        f32x4 s1 = *reinterpret_cast<const f32x4*>(gA + (size_t)8  * NND);
        f32x4 s2 = *reinterpret_cast<const f32x4*>(gA + (size_t)16 * NND);
        f32x4 s3 = *reinterpret_cast<const f32x4*>(gA + (size_t)24 * NND);
        bf16x4 p0, p1, p2, p3;
        p0[0]=(__bf16)s0[0]; p0[1]=(__bf16)s0[1]; p0[2]=(__bf16)s0[2]; p0[3]=(__bf16)s0[3];
        p1[0]=(__bf16)s1[0]; p1[1]=(__bf16)s1[1]; p1[2]=(__bf16)s1[2]; p1[3]=(__bf16)s1[3];
        p2[0]=(__bf16)s2[0]; p2[1]=(__bf16)s2[1]; p2[2]=(__bf16)s2[2]; p2[3]=(__bf16)s2[3];
        p3[0]=(__bf16)s3[0]; p3[1]=(__bf16)s3[1]; p3[2]=(__bf16)s3[2]; p3[3]=(__bf16)s3[3];
        *reinterpret_cast<bf16x4*>(&As[0][srow     ][scol]) = p0;
        *reinterpret_cast<bf16x4*>(&As[0][srow +  8][scol]) = p1;
        *reinterpret_cast<bf16x4*>(&As[0][srow + 16][scol]) = p2;
        *reinterpret_cast<bf16x4*>(&As[0][srow + 24][scol]) = p3;
    }
    __syncthreads();

    for (int t = 0; t < 8; ++t) {
        const int cur = t & 1;
        f32x4 n0, n1, n2, n3;
        const bool pf = (t < 7);
        if (pf) {                        // issue next-tile loads EARLY
            const float* g = gA + (t + 1) * 128;
            n0 = *reinterpret_cast<const f32x4*>(g);
            n1 = *reinterpret_cast<const f32x4*>(g + (size_t)8  * NND);
            n2 = *reinterpret_cast<const f32x4*>(g + (size_t)16 * NND);
            n3 = *reinterpret_cast<const f32x4*>(g + (size_t)24 * NND);
        }
        // compute tile t: 4 k-steps x (2 rows-tiles), operands LDS bf16 + L2-hot B
#pragma unroll
        for (int s = 0; s < 4; ++s) {
            const int ko = 32 * s + 8 * lg;
            bf16x8 aL = *reinterpret_cast<const bf16x8*>(&As[cur][l15     ][ko]);
            bf16x8 aH = *reinterpret_cast<const bf16x8*>(&As[cur][16 + l15][ko]);
            bf16x8 b  = *reinterpret_cast<const bf16x8*>(bp + t * 128 + 32 * s);
            accL = __builtin_amdgcn_mfma_f32_16x16x32_bf16(aL, b, accL, 0, 0, 0);
            accH = __builtin_amdgcn_mfma_f32_16x16x32_bf16(aH, b, accH, 0, 0, 0);
        }
        if (pf) {                        // cvt + write tile t+1 into other buffer
            bf16x4 p0, p1, p2, p3;
            p0[0]=(__bf16)n0[0]; p0[1]=(__bf16)n0[1]; p0[2]=(__bf16)n0[2]; p0[3]=(__bf16)n0[3];
            p1[0]=(__bf16)n1[0]; p1[1]=(__bf16)n1[1]; p1[2]=(__bf16)n1[2]; p1[3]=(__bf16)n1[3];
            p2[0]=(__bf16)n2[0]; p2[1]=(__bf16)n2[1]; p2[2]=(__bf16)n2[2]; p2[3]=(__bf16)n2[3];
            p3[0]=(__bf16)n3[0]; p3[1]=(__bf16)n3[1]; p3[2]=(__bf16)n3[2]; p3[3]=(__bf16)n3[3];
            *reinterpret_cast<bf16x4*>(&As[cur ^ 1][srow     ][scol]) = p0;
            *reinterpret_cast<bf16x4*>(&As[cur ^ 1][srow +  8][scol]) = p1;
            *reinterpret_cast<bf16x4*>(&As[cur ^ 1][srow + 16][scol]) = p2;
            *reinterpret_cast<bf16x4*>(&As[cur ^ 1][srow + 24][scol]) = p3;
        }
        __syncthreads();                 // single barrier: publishes t+1, retires t
    }

    // ---- store partials: C/D col=l15 (dim in quarter), row=lg*4+i
    float* pp = pws + (size_t)kw * NND * DIM;
#pragma unroll
    for (int i = 0; i < 4; ++i) {
        pp[(size_t)(R0 +      lg * 4 + i) * DIM + 16 * w + l15] = accL[i];
        pp[(size_t)(R0 + 16 + lg * 4 + i) * DIM + 16 * w + l15] = accH[i];
    }
}

// Kernel 3: sum 8 k-window partials (pair tree) + fused epilogue. 1 row/wave.
__global__ __launch_bounds__(256) void k_fin(
    const float* __restrict__ pws, float* __restrict__ out)
{
    const int tid  = threadIdx.x;
    const int lane = tid & 63;
    const int wave = tid >> 6;
    const int row  = blockIdx.x * 4 + wave;
    const size_t base = (size_t)row * DIM + lane;
    const size_t S = (size_t)NND * DIM;
    float hv = (((pws[base] + pws[S + base]) + (pws[2*S + base] + pws[3*S + base]))
             +  ((pws[4*S + base] + pws[5*S + base]) + (pws[6*S + base] + pws[7*S + base])));
    out[base] = epilogue_chain(hv, lane);
}

extern "C" void kernel_launch(void* const* d_in, const int* in_sizes, int n_in,
                              void* d_out, int out_size, void* d_ws, size_t ws_size,
                              hipStream_t stream)
{
    const float* x      = (const float*)d_in[0];
    const float* adj    = (const float*)d_in[1];
    const float* weight = (const float*)d_in[2];
    const float* bias   = (const float*)d_in[3];
    float* out = (float*)d_out;
    __bf16* l2bf = (__bf16*)d_ws;                          // 64 x PB bf16 = 1.33 MB
    float*  pws  = (float*)((char*)d_ws + 0x180000);       // 8 x 2 MB partials

    k_prep<<<2048, 256, 0, stream>>>(x, weight, bias, l2bf);
    k_mm<<<2048, 256, 0, stream>>>(adj, l2bf, pws);
    k_fin<<<2048, 256, 0, stream>>>(pws, out);
}